// Round 2
// baseline (554.313 us; speedup 1.0000x reference)
//
#include <hip/hip_runtime.h>

// GateRecurrent2dnoind: left-to-right SPN scan over W, 3-point stencil along H.
// [N=8, C=64, H=256, W=256] fp32.
//
// One WAVE per (n,c) plane. Lane l owns rows 4l..4l+3 (consecutive), so the
// vertical neighbor exchange is 2 intra-wave shuffles per W-step — no LDS,
// no barriers. Inputs stream directly to registers (float4 along W, WT=4),
// software-pipelined A/B so ~16KB of loads per wave stay in flight under the
// sequential scan. Output accumulated in registers, stored float4 per row.

constexpr int H  = 256;
constexpr int W  = 256;
constexpr int WT = 4;          // columns per tile (one float4)
constexpr int NT = W / WT;     // 64 tiles

struct Tile {
    float4 x[4], g1[4], g2[4], g3[4];   // [row 0..3] x 4 cols
};

__device__ __forceinline__
void load_tile(Tile& t, const float* __restrict__ px, const float* __restrict__ p1,
               const float* __restrict__ p2, const float* __restrict__ p3, int w)
{
#pragma unroll
    for (int r = 0; r < 4; ++r) {
        t.x [r] = *reinterpret_cast<const float4*>(px + r * W + w);
        t.g1[r] = *reinterpret_cast<const float4*>(p1 + r * W + w);
        t.g2[r] = *reinterpret_cast<const float4*>(p2 + r * W + w);
        t.g3[r] = *reinterpret_cast<const float4*>(p3 + r * W + w);
    }
}

__device__ __forceinline__
void compute_tile(const Tile& t, float h[4], float4 o[4], int lane)
{
#pragma unroll
    for (int c = 0; c < 4; ++c) {
        // previous-column h of vertical neighbors (cross-lane)
        float up = __shfl_up (h[3], 1);   // lane-1's row 4l-1
        float dn = __shfl_down(h[0], 1);  // lane+1's row 4l+4
        up = (lane == 0)  ? 0.0f : up;
        dn = (lane == 63) ? 0.0f : dn;
        float n0, n1, n2, n3;
        {
            const float x  = (&t.x [0].x)[c], g1 = (&t.g1[0].x)[c];
            const float g2 = (&t.g2[0].x)[c], g3 = (&t.g3[0].x)[c];
            const float a  = 1.0f - g1 - g2 - g3;
            n0 = fmaf(g3, h[1], fmaf(g2, h[0], fmaf(g1, up,   x * a)));
        }
        {
            const float x  = (&t.x [1].x)[c], g1 = (&t.g1[1].x)[c];
            const float g2 = (&t.g2[1].x)[c], g3 = (&t.g3[1].x)[c];
            const float a  = 1.0f - g1 - g2 - g3;
            n1 = fmaf(g3, h[2], fmaf(g2, h[1], fmaf(g1, h[0], x * a)));
        }
        {
            const float x  = (&t.x [2].x)[c], g1 = (&t.g1[2].x)[c];
            const float g2 = (&t.g2[2].x)[c], g3 = (&t.g3[2].x)[c];
            const float a  = 1.0f - g1 - g2 - g3;
            n2 = fmaf(g3, h[3], fmaf(g2, h[2], fmaf(g1, h[1], x * a)));
        }
        {
            const float x  = (&t.x [3].x)[c], g1 = (&t.g1[3].x)[c];
            const float g2 = (&t.g2[3].x)[c], g3 = (&t.g3[3].x)[c];
            const float a  = 1.0f - g1 - g2 - g3;
            n3 = fmaf(g3, dn,   fmaf(g2, h[3], fmaf(g1, h[2], x * a)));
        }
        h[0] = n0; h[1] = n1; h[2] = n2; h[3] = n3;
        (&o[0].x)[c] = n0; (&o[1].x)[c] = n1; (&o[2].x)[c] = n2; (&o[3].x)[c] = n3;
    }
}

__device__ __forceinline__
void store_tile(float* __restrict__ po, const float4 o[4], int w)
{
#pragma unroll
    for (int r = 0; r < 4; ++r)
        *reinterpret_cast<float4*>(po + r * W + w) = o[r];
}

__global__ __launch_bounds__(64)
void spn_scan_regs(const float* __restrict__ X,  const float* __restrict__ G1,
                   const float* __restrict__ G2, const float* __restrict__ G3,
                   float* __restrict__ O)
{
    const int lane = threadIdx.x;                       // 0..63
    const size_t base = (size_t)blockIdx.x * (H * W) + (size_t)(lane * 4) * W;
    const float* px = X  + base;
    const float* p1 = G1 + base;
    const float* p2 = G2 + base;
    const float* p3 = G3 + base;
    float*       po = O  + base;

    float  h[4] = {0.0f, 0.0f, 0.0f, 0.0f};
    float4 o[4];
    Tile A, B;

    load_tile(A, px, p1, p2, p3, 0);
    load_tile(B, px, p1, p2, p3, WT);

    for (int t0 = 0; t0 < NT; t0 += 2) {
        // ---- tile t0 from A; prefetch t0+2 into A afterwards ----
        compute_tile(A, h, o, lane);
        store_tile(po, o, t0 * WT);
        {
            int wn = (t0 + 2) * WT;           // clamp last prefetches (data unused)
            if (wn > W - WT) wn = W - WT;
            load_tile(A, px, p1, p2, p3, wn);
        }
        // ---- tile t0+1 from B; prefetch t0+3 into B afterwards ----
        compute_tile(B, h, o, lane);
        store_tile(po, o, (t0 + 1) * WT);
        {
            int wn = (t0 + 3) * WT;
            if (wn > W - WT) wn = W - WT;
            load_tile(B, px, p1, p2, p3, wn);
        }
    }
}

extern "C" void kernel_launch(void* const* d_in, const int* in_sizes, int n_in,
                              void* d_out, int out_size, void* d_ws, size_t ws_size,
                              hipStream_t stream) {
    const float* X  = (const float*)d_in[0];
    const float* G1 = (const float*)d_in[1];
    const float* G2 = (const float*)d_in[2];
    const float* G3 = (const float*)d_in[3];
    float* O = (float*)d_out;

    const int planes = 8 * 64;   // N*C = 512 waves, one per plane
    spn_scan_regs<<<dim3(planes), dim3(64), 0, stream>>>(X, G1, G2, G3, O);
}

// Round 3
// 522.556 us; speedup vs baseline: 1.0608x; 1.0608x over previous
//
#include <hip/hip_runtime.h>
#include <cstdint>

// GateRecurrent2dnoind: left-to-right SPN scan over W, 3-pt stencil along H.
// [N=8, C=64, H=256, W=256] fp32.
//
// One single-wave block per (n,c) plane (512 blocks, 2/CU). Lane l owns rows
// 4l..4l+3 -> vertical exchange = 2 intra-wave shuffles per step, no barriers.
// Inputs staged global->LDS via __builtin_amdgcn_global_load_lds (16B/lane),
// double-buffered 8-col tiles (2 x 32KB = 64KB LDS), counted s_waitcnt
// vmcnt(32) so one tile of loads is always in flight. LDS layout
// [buf][arr][s][r][lane] float4: scan reads ds_read_b128 with 16B-slot == lane
// -> 2-way bank aliasing (free). Outputs accumulate in regs over 16 cols, then
// 4x float4 per row (full 64B line) -> stores merge in L2.

constexpr int H  = 256;
constexpr int W  = 256;
constexpr int WT = 8;          // cols per tile
constexpr int NT = W / WT;     // 32 tiles

#define F4C(v, j) ((&(v).x)[j])

typedef const __attribute__((address_space(1))) void* gas_ptr;
typedef __attribute__((address_space(3))) void* las_ptr;

__device__ __forceinline__ void gload_lds16(const float* g, float4* l) {
    __builtin_amdgcn_global_load_lds((gas_ptr)(const void*)g, (las_ptr)(void*)l,
                                     16, 0, 0);
}

__global__ __launch_bounds__(64)
void spn_wave(const float* __restrict__ X,  const float* __restrict__ G1,
              const float* __restrict__ G2, const float* __restrict__ G3,
              float* __restrict__ O)
{
    // [buf][array][s(col-slot)][r(row%4)][lane] : 2*4*2*4*64 float4 = 64 KiB
    __shared__ float4 lds[2][4][2][4][64];

    const int    l  = threadIdx.x;                       // 0..63
    const size_t pb = (size_t)blockIdx.x * (H * W);
    const float* __restrict__ in0 = X  + pb;
    const float* __restrict__ in1 = G1 + pb;
    const float* __restrict__ in2 = G2 + pb;
    const float* __restrict__ in3 = G3 + pb;
    float* __restrict__ out = O + pb;

    // issue the 32 global->LDS loads for tile t into buffer b
    auto issue = [&](int t, int b) {
        const int w = t * WT;
#pragma unroll
        for (int s = 0; s < 2; ++s)
#pragma unroll
            for (int r = 0; r < 4; ++r) {
                const int goff = (4 * l + r) * W + w + 4 * s;
                gload_lds16(in0 + goff, &lds[b][0][s][r][0]);
                gload_lds16(in1 + goff, &lds[b][1][s][r][0]);
                gload_lds16(in2 + goff, &lds[b][2][s][r][0]);
                gload_lds16(in3 + goff, &lds[b][3][s][r][0]);
            }
    };

    issue(0, 0);
    issue(1, 1);

    float h0 = 0.f, h1 = 0.f, h2 = 0.f, h3 = 0.f;
    float4 o[4][4];                      // [r][16 cols as 4 x float4]

    for (int p = 0; p < NT / 2; ++p) {
#pragma unroll
        for (int half = 0; half < 2; ++half) {
            const int  t       = 2 * p + half;
            const int  b       = half;               // buf = t & 1
            const bool steady  = (t + 2 < NT);

            // tile t's 32 loads retired (tile t+1's 32 may stay in flight)
            if (steady) asm volatile("s_waitcnt vmcnt(32)" ::: "memory");
            else        asm volatile("s_waitcnt vmcnt(0)"  ::: "memory");

            // LDS -> regs (ds_read_b128, 2-way bank aliasing = free)
            float4 xr[4][2], a1[4][2], a2[4][2], a3[4][2];
#pragma unroll
            for (int s = 0; s < 2; ++s)
#pragma unroll
                for (int r = 0; r < 4; ++r) {
                    xr[r][s] = lds[b][0][s][r][l];
                    a1[r][s] = lds[b][1][s][r][l];
                    a2[r][s] = lds[b][2][s][r][l];
                    a3[r][s] = lds[b][3][s][r][l];
                }
            // drain ds_reads before overwriting this buffer with tile t+2
            asm volatile("s_waitcnt lgkmcnt(0)" ::: "memory");
            if (steady) issue(t + 2, b);

            // 8 sequential scan steps (cols t*8 .. t*8+7)
#pragma unroll
            for (int s = 0; s < 2; ++s)
#pragma unroll
                for (int j = 0; j < 4; ++j) {
                    float up = __shfl_up(h3, 1);
                    float dn = __shfl_down(h0, 1);
                    if (l == 0)  up = 0.f;
                    if (l == 63) dn = 0.f;

                    const float x0 = F4C(xr[0][s], j), g10 = F4C(a1[0][s], j),
                                g20 = F4C(a2[0][s], j), g30 = F4C(a3[0][s], j);
                    const float x1 = F4C(xr[1][s], j), g11 = F4C(a1[1][s], j),
                                g21 = F4C(a2[1][s], j), g31 = F4C(a3[1][s], j);
                    const float x2 = F4C(xr[2][s], j), g12 = F4C(a1[2][s], j),
                                g22 = F4C(a2[2][s], j), g32 = F4C(a3[2][s], j);
                    const float x3 = F4C(xr[3][s], j), g13 = F4C(a1[3][s], j),
                                g23 = F4C(a2[3][s], j), g33 = F4C(a3[3][s], j);

                    const float n0 = fmaf(g30, h1, fmaf(g20, h0,
                                     fmaf(g10, up, x0 * (1.f - g10 - g20 - g30))));
                    const float n1 = fmaf(g31, h2, fmaf(g21, h1,
                                     fmaf(g11, h0, x1 * (1.f - g11 - g21 - g31))));
                    const float n2 = fmaf(g32, h3, fmaf(g22, h2,
                                     fmaf(g12, h1, x2 * (1.f - g12 - g22 - g32))));
                    const float n3 = fmaf(g33, dn, fmaf(g23, h3,
                                     fmaf(g13, h2, x3 * (1.f - g13 - g23 - g33))));

                    h0 = n0; h1 = n1; h2 = n2; h3 = n3;
                    const int oc = half * 2 + s;     // static after unroll
                    F4C(o[0][oc], j) = n0;
                    F4C(o[1][oc], j) = n1;
                    F4C(o[2][oc], j) = n2;
                    F4C(o[3][oc], j) = n3;
                }
        }

        // store the pair's 16 cols: 4 x float4 per row = full 64B line
        const int wp = p * 16;
#pragma unroll
        for (int r = 0; r < 4; ++r) {
            float* po = out + (4 * l + r) * W + wp;
            *reinterpret_cast<float4*>(po)      = o[r][0];
            *reinterpret_cast<float4*>(po + 4)  = o[r][1];
            *reinterpret_cast<float4*>(po + 8)  = o[r][2];
            *reinterpret_cast<float4*>(po + 12) = o[r][3];
        }
    }
}

extern "C" void kernel_launch(void* const* d_in, const int* in_sizes, int n_in,
                              void* d_out, int out_size, void* d_ws, size_t ws_size,
                              hipStream_t stream) {
    const float* X  = (const float*)d_in[0];
    const float* G1 = (const float*)d_in[1];
    const float* G2 = (const float*)d_in[2];
    const float* G3 = (const float*)d_in[3];
    float* O = (float*)d_out;

    const int planes = 8 * 64;   // N*C = 512 single-wave blocks
    spn_wave<<<dim3(planes), dim3(64), 0, stream>>>(X, G1, G2, G3, O);
}

// Round 4
// 276.591 us; speedup vs baseline: 2.0041x; 1.8893x over previous
//
#include <hip/hip_runtime.h>

// GateRecurrent2dnoind: left-to-right SPN scan over W, 3-pt stencil along H.
// [N=8, C=64, H=256, W=256] fp32.
//
// One single-wave block per (n,c) plane. Lane l owns rows 4l..4l+3 ->
// vertical exchange = 2 shuffles/step, zero barriers. Staging via
// global_load_lds with LINE-COVERING lane groups (8 lanes = 4 rows x 32B
// contiguous) and a per-lane XOR pre-swizzle of the global source so the
// scan-side ds_read_b128 (slot S = 8l + ((2r+cg)^(l&7))) is phase-balanced
// (conflict-free). 4 half-buffers (8 cols each, 128KB LDS), counted
// s_waitcnt vmcnt(48) -> ~2 half-tiles always in flight, never drained.

constexpr int H  = 256;
constexpr int W  = 256;
constexpr int HC = 8;           // cols per half-tile
constexpr int NH = W / HC;      // 32 half-tiles

#define F4C(v, j) ((&(v).x)[j])
#define WAITV(N) asm volatile("s_waitcnt vmcnt(" #N ")" ::: "memory")

typedef const __attribute__((address_space(1))) void* gas_ptr;
typedef __attribute__((address_space(3))) void* las_ptr;

__device__ __forceinline__ void gl16(const float* g, float4* l) {
    __builtin_amdgcn_global_load_lds((gas_ptr)(const void*)g, (las_ptr)(void*)l,
                                     16, 0, 0);
}

// read 16 x ds_read_b128 (column-group CG of a half-buffer), then 4 scan steps
template<int CG>
__device__ __forceinline__
void scan4(const float4 (*A)[512], int l, int lx,
           float& h0, float& h1, float& h2, float& h3,
           float4& o0, float4& o1, float4& o2, float4& o3)
{
    float4 q0[4], q1[4], q2[4], q3[4];          // [array], rows r=0..3
    const int s8 = 8 * l;
#pragma unroll
    for (int a = 0; a < 4; ++a) {
        q0[a] = A[a][s8 + ((0 + CG) ^ lx)];
        q1[a] = A[a][s8 + ((2 + CG) ^ lx)];
        q2[a] = A[a][s8 + ((4 + CG) ^ lx)];
        q3[a] = A[a][s8 + ((6 + CG) ^ lx)];
    }
#pragma unroll
    for (int j = 0; j < 4; ++j) {
        float up = __shfl_up(h3, 1);            // lane-1's row 4l-1
        float dn = __shfl_down(h0, 1);          // lane+1's row 4l+4
        if (l == 0)  up = 0.f;
        if (l == 63) dn = 0.f;

        const float x0 = F4C(q0[0], j), a10 = F4C(q0[1], j),
                    a20 = F4C(q0[2], j), a30 = F4C(q0[3], j);
        const float x1 = F4C(q1[0], j), a11 = F4C(q1[1], j),
                    a21 = F4C(q1[2], j), a31 = F4C(q1[3], j);
        const float x2 = F4C(q2[0], j), a12 = F4C(q2[1], j),
                    a22 = F4C(q2[2], j), a32 = F4C(q2[3], j);
        const float x3 = F4C(q3[0], j), a13 = F4C(q3[1], j),
                    a23 = F4C(q3[2], j), a33 = F4C(q3[3], j);

        const float n0 = fmaf(a30, h1, fmaf(a20, h0,
                         fmaf(a10, up, x0 * (1.f - a10 - a20 - a30))));
        const float n1 = fmaf(a31, h2, fmaf(a21, h1,
                         fmaf(a11, h0, x1 * (1.f - a11 - a21 - a31))));
        const float n2 = fmaf(a32, h3, fmaf(a22, h2,
                         fmaf(a12, h1, x2 * (1.f - a12 - a22 - a32))));
        const float n3 = fmaf(a33, dn, fmaf(a23, h3,
                         fmaf(a13, h2, x3 * (1.f - a13 - a23 - a33))));

        h0 = n0; h1 = n1; h2 = n2; h3 = n3;
        F4C(o0, j) = n0; F4C(o1, j) = n1; F4C(o2, j) = n2; F4C(o3, j) = n3;
    }
}

__global__ __launch_bounds__(64)
void spn_wave(const float* __restrict__ X,  const float* __restrict__ G1,
              const float* __restrict__ G2, const float* __restrict__ G3,
              float* __restrict__ O)
{
    __shared__ float4 lds4[4][4][512];   // [half-buf][array][16B slot] = 128 KiB

    const int l  = threadIdx.x;          // 0..63
    const int lx = l & 7;
    const size_t pb = (size_t)blockIdx.x * (size_t)(H * W);

    // inverse-swizzled per-lane global offset: lane j loads granule
    // G = 64i + (j ^ ((j>>3)&7)); G = R_local*2 + cc
    const int jp      = l ^ ((l >> 3) & 7);
    const int laneoff = (jp >> 1) * W + (jp & 1) * 4;

    const float* i0 = X  + pb + laneoff;
    const float* i1 = G1 + pb + laneoff;
    const float* i2 = G2 + pb + laneoff;
    const float* i3 = G3 + pb + laneoff;
    float* out = O + pb + (size_t)(4 * l) * W;

    // issue the 32 global->LDS loads of half-tile h into buffer h&3
    auto issue = [&](int h) {
        const int b    = h & 3;
        const int base = h * HC;
#pragma unroll
        for (int i = 0; i < 8; ++i) {
            const int go = base + i * (32 * W);   // rows 32i..32i+31
            gl16(i0 + go, &lds4[b][0][i * 64]);
            gl16(i1 + go, &lds4[b][1][i * 64]);
            gl16(i2 + go, &lds4[b][2][i * 64]);
            gl16(i3 + go, &lds4[b][3][i * 64]);
        }
    };

    issue(0);
    issue(1);

    float h0 = 0.f, h1 = 0.f, h2 = 0.f, h3 = 0.f;
    float4 o[4][4];                      // [row r][col-group oc]

#pragma unroll 1
    for (int p = 0; p < 16; ++p) {
        // ---- even half h = 2p (cols 16p .. 16p+7) ----
        const int he = 2 * p;
        if (p == 0) WAITV(32); else WAITV(48);
        {
            const float4 (*A)[512] = lds4[he & 3];
            scan4<0>(A, l, lx, h0, h1, h2, h3,
                     o[0][0], o[1][0], o[2][0], o[3][0]);
            if (he + 2 < NH) issue(he + 2);
            scan4<1>(A, l, lx, h0, h1, h2, h3,
                     o[0][1], o[1][1], o[2][1], o[3][1]);
        }

        // ---- odd half h = 2p+1 (cols 16p+8 .. 16p+15) ----
        const int ho = he + 1;
        if (p == 0) WAITV(32); else if (p == 15) WAITV(0); else WAITV(48);
        {
            const float4 (*A)[512] = lds4[ho & 3];
            scan4<0>(A, l, lx, h0, h1, h2, h3,
                     o[0][2], o[1][2], o[2][2], o[3][2]);
            if (ho + 2 < NH) issue(ho + 2);
            scan4<1>(A, l, lx, h0, h1, h2, h3,
                     o[0][3], o[1][3], o[2][3], o[3][3]);
        }

        // ---- store 16 cols x 4 rows (full 64B per row) ----
        const int wp = p * 16;
#pragma unroll
        for (int r = 0; r < 4; ++r) {
            float* po = out + r * W + wp;
            *reinterpret_cast<float4*>(po +  0) = o[r][0];
            *reinterpret_cast<float4*>(po +  4) = o[r][1];
            *reinterpret_cast<float4*>(po +  8) = o[r][2];
            *reinterpret_cast<float4*>(po + 12) = o[r][3];
        }
    }
}

extern "C" void kernel_launch(void* const* d_in, const int* in_sizes, int n_in,
                              void* d_out, int out_size, void* d_ws, size_t ws_size,
                              hipStream_t stream) {
    const float* X  = (const float*)d_in[0];
    const float* G1 = (const float*)d_in[1];
    const float* G2 = (const float*)d_in[2];
    const float* G3 = (const float*)d_in[3];
    float* O = (float*)d_out;

    const int planes = 8 * 64;   // N*C = 512 single-wave blocks, 2 per CU over 2 rounds
    spn_wave<<<dim3(planes), dim3(64), 0, stream>>>(X, G1, G2, G3, O);
}